// Round 6
// baseline (102.016 us; speedup 1.0000x reference)
//
#include <hip/hip_runtime.h>

#define N_ENT      1000000
#define N_REL      1000
#define DIM        128
#define R_TYPES    8
#define E_PER_TYPE 131072
#define SCORE_DIM  150000

typedef float f32x4 __attribute__((ext_vector_type(4)));

// ---------------------------------------------------------------------------
// Kernel 1: row sums of ent_table [1M x 128] f32 (+ fused rel_table [1000 x 128]).
// 8 lanes per row: lane loads 4 independent float4s (per-instruction: 8 rows
// x 128B contiguous segments, full cachelines). In-lane 15-add reduce, then
// 3 shfl-xor levels per 8 rows. Loads are NON-TEMPORAL (nt): this is a
// one-shot 512MB stream with zero reuse — don't thrash L2 with it.
// ---------------------------------------------------------------------------
__global__ void row_sum_kernel(const float* __restrict__ ent,
                               const float* __restrict__ rel,
                               float* __restrict__ ent_sums,
                               float* __restrict__ rel_sums) {
    const int tid     = blockIdx.x * blockDim.x + threadIdx.x;
    const int sub     = tid & 7;                          // lane within row
    const int g       = tid >> 3;                         // row group
    const int ngroups = (gridDim.x * blockDim.x) >> 3;    // 65536 @ 2048x256

    for (int r = g; r < N_ENT; r += ngroups) {
        const f32x4* rowp = reinterpret_cast<const f32x4*>(ent + (size_t)r * DIM);
        const f32x4 v0 = __builtin_nontemporal_load(rowp + sub);
        const f32x4 v1 = __builtin_nontemporal_load(rowp + sub + 8);
        const f32x4 v2 = __builtin_nontemporal_load(rowp + sub + 16);
        const f32x4 v3 = __builtin_nontemporal_load(rowp + sub + 24);

        float s = ((v0.x + v0.y) + (v0.z + v0.w))
                + ((v1.x + v1.y) + (v1.z + v1.w))
                + ((v2.x + v2.y) + (v2.z + v2.w))
                + ((v3.x + v3.y) + (v3.z + v3.w));
        s += __shfl_xor(s, 1, 64);
        s += __shfl_xor(s, 2, 64);
        s += __shfl_xor(s, 4, 64);
        if (sub == 0) ent_sums[r] = s;                    // 8 consecutive rows/wave
    }

    // Fused tiny rel row sums (first 1000 groups, one row each). Cached loads
    // (tiny, and harmless either way).
    if (g < N_REL) {
        const float4* rowp = reinterpret_cast<const float4*>(rel + (size_t)g * DIM);
        const float4 v0 = rowp[sub];
        const float4 v1 = rowp[sub + 8];
        const float4 v2 = rowp[sub + 16];
        const float4 v3 = rowp[sub + 24];
        float s = ((v0.x + v0.y) + (v0.z + v0.w))
                + ((v1.x + v1.y) + (v1.z + v1.w))
                + ((v2.x + v2.y) + (v2.z + v2.w))
                + ((v3.x + v3.y) + (v3.z + v3.w));
        s += __shfl_xor(s, 1, 64);
        s += __shfl_xor(s, 2, 64);
        s += __shfl_xor(s, 4, 64);
        if (sub == 0) rel_sums[g] = s;
    }
}

// ---------------------------------------------------------------------------
// Kernel 2: 4 output elements per thread, 2D grid (y = relation type, so no
// integer division). int4 index loads (16B/lane) + float4 store. SCORE_DIM
// and E_PER_TYPE both %4==0, so a 4-group never straddles boundaries.
// ---------------------------------------------------------------------------
__global__ void edge_score_kernel(const int* __restrict__ src_idx,
                                  const int* __restrict__ dst_idx,
                                  const int* __restrict__ rel_idx,
                                  const float* __restrict__ ent_sums,
                                  const float* __restrict__ rel_sums,
                                  float* __restrict__ out) {
    const int rt = blockIdx.y;
    const int e  = (blockIdx.x * blockDim.x + threadIdx.x) * 4;
    if (e >= SCORE_DIM) return;

    float4 v = make_float4(0.f, 0.f, 0.f, 0.f);
    if (e < E_PER_TYPE) {
        const int ei = rt * E_PER_TYPE + e;               // 16B-aligned
        const int4 s4 = *reinterpret_cast<const int4*>(src_idx + ei);
        const int4 d4 = *reinterpret_cast<const int4*>(dst_idx + ei);
        const int4 r4 = *reinterpret_cast<const int4*>(rel_idx + ei);
        v.x = ent_sums[s4.x] + rel_sums[r4.x] - ent_sums[d4.x];
        v.y = ent_sums[s4.y] + rel_sums[r4.y] - ent_sums[d4.y];
        v.z = ent_sums[s4.z] + rel_sums[r4.z] - ent_sums[d4.z];
        v.w = ent_sums[s4.w] + rel_sums[r4.w] - ent_sums[d4.w];
    }
    *reinterpret_cast<float4*>(out + (size_t)rt * SCORE_DIM + e) = v;
}

extern "C" void kernel_launch(void* const* d_in, const int* in_sizes, int n_in,
                              void* d_out, int out_size, void* d_ws, size_t ws_size,
                              hipStream_t stream) {
    const float* ent_table = (const float*)d_in[0];
    const float* rel_table = (const float*)d_in[1];
    const int*   src_idx   = (const int*)d_in[2];
    const int*   dst_idx   = (const int*)d_in[3];
    const int*   rel_idx   = (const int*)d_in[4];
    float* out = (float*)d_out;

    // Workspace: [0, 4MB) ent row sums, [4MB, +4KB) rel row sums.
    float* ent_sums = (float*)d_ws;
    float* rel_sums = (float*)((char*)d_ws + (size_t)N_ENT * sizeof(float));

    // Kernel 1: 2048 blocks x 256 = 32 waves/CU in one shot (max occupancy),
    // 65536 row-groups of 8 lanes, ~15.3 rows/group. HBM-bound: 512 MB read.
    row_sum_kernel<<<2048, 256, 0, stream>>>(ent_table, rel_table,
                                             ent_sums, rel_sums);

    // Kernel 2: scores + padding, 4 elements/thread, grid.y = relation type.
    {
        const int blocks_x = (SCORE_DIM / 4 + 255) / 256;   // 147
        dim3 grid(blocks_x, R_TYPES);
        edge_score_kernel<<<grid, 256, 0, stream>>>(
            src_idx, dst_idx, rel_idx, ent_sums, rel_sums, out);
    }
}

// Round 7
// 97.788 us; speedup vs baseline: 1.0432x; 1.0432x over previous
//
#include <hip/hip_runtime.h>

#define N_ENT      1000000
#define N_REL      1000
#define DIM        128
#define R_TYPES    8
#define E_PER_TYPE 131072
#define SCORE_DIM  150000

typedef float f32x4 __attribute__((ext_vector_type(4)));
typedef int   i32x4 __attribute__((ext_vector_type(4)));

// ---------------------------------------------------------------------------
// Kernel 1: row sums of ent_table [1M x 128] f32 (+ fused rel_table [1000 x 128]).
// ONE 8-lane group per row, no grid-stride loop: 31250 blocks x 256 threads
// = exactly 1M groups (8M lanes). Eliminates the 15-vs-16-iteration tail of
// the grid-stride version (74% of the machine idled during the last pass).
// Per load instruction a wave covers 8 rows x 128B contiguous segments.
// Loads are non-temporal: one-shot 512MB stream, zero reuse.
// ---------------------------------------------------------------------------
__global__ void row_sum_kernel(const float* __restrict__ ent,
                               const float* __restrict__ rel,
                               float* __restrict__ ent_sums,
                               float* __restrict__ rel_sums) {
    const int tid = blockIdx.x * blockDim.x + threadIdx.x;
    const int sub = tid & 7;                 // lane within row
    const int r   = tid >> 3;                // row (exactly covers [0, 1M))

    const f32x4* rowp = reinterpret_cast<const f32x4*>(ent + (size_t)r * DIM);
    const f32x4 v0 = __builtin_nontemporal_load(rowp + sub);
    const f32x4 v1 = __builtin_nontemporal_load(rowp + sub + 8);
    const f32x4 v2 = __builtin_nontemporal_load(rowp + sub + 16);
    const f32x4 v3 = __builtin_nontemporal_load(rowp + sub + 24);

    float s = ((v0.x + v0.y) + (v0.z + v0.w))
            + ((v1.x + v1.y) + (v1.z + v1.w))
            + ((v2.x + v2.y) + (v2.z + v2.w))
            + ((v3.x + v3.y) + (v3.z + v3.w));
    s += __shfl_xor(s, 1, 64);
    s += __shfl_xor(s, 2, 64);
    s += __shfl_xor(s, 4, 64);
    if (sub == 0) ent_sums[r] = s;           // 8 consecutive rows per wave

    // Fused tiny rel row sums (first 1000 groups do one extra row).
    if (r < N_REL) {
        const float4* rp = reinterpret_cast<const float4*>(rel + (size_t)r * DIM);
        const float4 a0 = rp[sub];
        const float4 a1 = rp[sub + 8];
        const float4 a2 = rp[sub + 16];
        const float4 a3 = rp[sub + 24];
        float t = ((a0.x + a0.y) + (a0.z + a0.w))
                + ((a1.x + a1.y) + (a1.z + a1.w))
                + ((a2.x + a2.y) + (a2.z + a2.w))
                + ((a3.x + a3.y) + (a3.z + a3.w));
        t += __shfl_xor(t, 1, 64);
        t += __shfl_xor(t, 2, 64);
        t += __shfl_xor(t, 4, 64);
        if (sub == 0) rel_sums[r] = t;
    }
}

// ---------------------------------------------------------------------------
// Kernel 2: 4 output elements per thread, 2D grid (y = relation type).
// Index streams + output store are non-temporal (read/write-once) so the
// only L2-resident traffic is the ent_sums/rel_sums gather working set.
// ---------------------------------------------------------------------------
__global__ void edge_score_kernel(const int* __restrict__ src_idx,
                                  const int* __restrict__ dst_idx,
                                  const int* __restrict__ rel_idx,
                                  const float* __restrict__ ent_sums,
                                  const float* __restrict__ rel_sums,
                                  float* __restrict__ out) {
    const int rt = blockIdx.y;
    const int e  = (blockIdx.x * blockDim.x + threadIdx.x) * 4;
    if (e >= SCORE_DIM) return;

    f32x4 v = {0.f, 0.f, 0.f, 0.f};
    if (e < E_PER_TYPE) {
        const int ei = rt * E_PER_TYPE + e;               // 16B-aligned
        const i32x4 s4 = __builtin_nontemporal_load(
            reinterpret_cast<const i32x4*>(src_idx + ei));
        const i32x4 d4 = __builtin_nontemporal_load(
            reinterpret_cast<const i32x4*>(dst_idx + ei));
        const i32x4 r4 = __builtin_nontemporal_load(
            reinterpret_cast<const i32x4*>(rel_idx + ei));
        v.x = ent_sums[s4.x] + rel_sums[r4.x] - ent_sums[d4.x];
        v.y = ent_sums[s4.y] + rel_sums[r4.y] - ent_sums[d4.y];
        v.z = ent_sums[s4.z] + rel_sums[r4.z] - ent_sums[d4.z];
        v.w = ent_sums[s4.w] + rel_sums[r4.w] - ent_sums[d4.w];
    }
    __builtin_nontemporal_store(
        v, reinterpret_cast<f32x4*>(out + (size_t)rt * SCORE_DIM + e));
}

extern "C" void kernel_launch(void* const* d_in, const int* in_sizes, int n_in,
                              void* d_out, int out_size, void* d_ws, size_t ws_size,
                              hipStream_t stream) {
    const float* ent_table = (const float*)d_in[0];
    const float* rel_table = (const float*)d_in[1];
    const int*   src_idx   = (const int*)d_in[2];
    const int*   dst_idx   = (const int*)d_in[3];
    const int*   rel_idx   = (const int*)d_in[4];
    float* out = (float*)d_out;

    // Workspace: [0, 4MB) ent row sums, [4MB, +4KB) rel row sums.
    float* ent_sums = (float*)d_ws;
    float* rel_sums = (float*)((char*)d_ws + (size_t)N_ENT * sizeof(float));

    // Kernel 1: 31250 blocks x 256 threads = exactly 1M 8-lane row groups.
    // HW dispatcher load-balances; no software grid-stride tail.
    row_sum_kernel<<<31250, 256, 0, stream>>>(ent_table, rel_table,
                                              ent_sums, rel_sums);

    // Kernel 2: scores + padding, 4 elements/thread, grid.y = relation type.
    {
        const int blocks_x = (SCORE_DIM / 4 + 255) / 256;   // 147
        dim3 grid(blocks_x, R_TYPES);
        edge_score_kernel<<<grid, 256, 0, stream>>>(
            src_idx, dst_idx, rel_idx, ent_sums, rel_sums, out);
    }
}